// Round 10
// baseline (167.966 us; speedup 1.0000x reference)
//
#include <hip/hip_runtime.h>
#include <hip/hip_fp16.h>

// AxialAttention on MI355X (gfx950).
// x: [8,128,128,128] fp32, attend along H. Problem = (n0,h,w): S=128, d=16.
// K1 (attn): fully-MFMA, h-pair pipelined. Block = 512 thr / 8 waves owns an
//   8-w stripe x TWO h values, double-buffered 40KB LDS each. Timeline:
//     stage(h0,buf0) -> bar -> [issue h1 global loads to regs]
//     compute(h0)  (MFMA/exp hides h1 HBM latency)      <- T14 overlap
//     pack+ds_write(h1,buf1) -> bar -> compute(h1)
//   This breaks rounds 4-9's ~50us plateau: the old single-problem kernel was
//   a barrier-separated memory-burst + compute-burst with zero overlap.
//   Fragment chain (D==A/B layout identity of 16x16x16 MFMA):
//     Q^T = mfma(Wq, y^T) (scaled by 1/sqrt(128)*log2e), K^T = mfma(Wk, y^T),
//     V = mfma(y, Wv^T), P^T = exp2(mfma(K, Q)) via cvt_pkrtz, O = mfma(P, V).
//   AO written bf16 [b=(n0,w)][s][c]. Wo->bf16 prep folded in (32 elem/block).
//   __launch_bounds__(512,4): VGPR cap 128 (cap 64 = round-6 spill disaster).
// K2 (proj): block=(n0,s,w-half). Wo A-frags preloaded to regs, AO half-tile
//   staged to LDS (batched loads), 4 waves x (32e x 64w) 16x16x32 bf16 MFMA.

typedef __attribute__((ext_vector_type(4))) float f32x4;
typedef __attribute__((ext_vector_type(4))) _Float16 f16x4;
typedef __attribute__((ext_vector_type(2))) __fp16 fp16x2r;  // cvt_pkrtz native type
typedef __attribute__((ext_vector_type(8))) short bf16x8;

__device__ __forceinline__ unsigned int bf16_rne(float x) {
    unsigned int u = __float_as_uint(x);
    return (u + 0x7fffu + ((u >> 16) & 1u)) >> 16;
}
__device__ __forceinline__ unsigned int pack_half2(float a, float b) {
    __half2 h = __floats2half2_rn(a, b);
    return *reinterpret_cast<unsigned int*>(&h);
}

// One problem's full attention given its staged LDS x-tile. Writes AO.
__device__ __forceinline__ void attn_compute(
    const unsigned int* xsbuf, int wvi, int lr, int lg,
    f16x4 fq, f16x4 fk, f16x4 fv, float qsc,
    unsigned short* __restrict__ aob)
{
    const f32x4 zf = {0.f, 0.f, 0.f, 0.f};

    // y fragments from LDS: yf[rt][j] = y[rt*16+lr][lg*4+j]
    const char* yb = (const char*)xsbuf + wvi * 5120 + lr * 40 + lg * 8;
    f16x4 yf[8];
    #pragma unroll
    for (int rt = 0; rt < 8; ++rt)
        yf[rt] = *(const f16x4*)(yb + rt * 640);   // 16 rows * 40B

    // Projections: per 16-row tile t.
    f16x4 qb[8], ka[8], vb[8];
    #pragma unroll
    for (int t = 0; t < 8; ++t) {
        f32x4 qt = __builtin_amdgcn_mfma_f32_16x16x16f16(fq, yf[t], zf, 0, 0, 0);
        f32x4 kt = __builtin_amdgcn_mfma_f32_16x16x16f16(fk, yf[t], zf, 0, 0, 0);
        f32x4 vt = __builtin_amdgcn_mfma_f32_16x16x16f16(yf[t], fv, zf, 0, 0, 0);
        qb[t] = (f16x4){(_Float16)(qt[0] * qsc), (_Float16)(qt[1] * qsc),
                        (_Float16)(qt[2] * qsc), (_Float16)(qt[3] * qsc)};
        ka[t] = (f16x4){(_Float16)kt[0], (_Float16)kt[1], (_Float16)kt[2], (_Float16)kt[3]};
        vb[t] = (f16x4){(_Float16)vt[0], (_Float16)vt[1], (_Float16)vt[2], (_Float16)vt[3]};
    }

    #pragma unroll
    for (int qt = 0; qt < 8; ++qt) {
        f32x4 s[8];
        #pragma unroll
        for (int kt = 0; kt < 8; ++kt)
            s[kt] = __builtin_amdgcn_mfma_f32_16x16x16f16(ka[kt], qb[qt], zf, 0, 0, 0);
        float sum = 0.f;
        f16x4 pa[8];
        #pragma unroll
        for (int kt = 0; kt < 8; ++kt) {
            float p0 = __builtin_amdgcn_exp2f(s[kt][0]);
            float p1 = __builtin_amdgcn_exp2f(s[kt][1]);
            float p2 = __builtin_amdgcn_exp2f(s[kt][2]);
            float p3 = __builtin_amdgcn_exp2f(s[kt][3]);
            sum += (p0 + p1) + (p2 + p3);
            union { fp16x2r h2[2]; f16x4 h4; } up;
            up.h2[0] = __builtin_amdgcn_cvt_pkrtz(p0, p1);
            up.h2[1] = __builtin_amdgcn_cvt_pkrtz(p2, p3);
            pa[kt] = up.h4;
        }
        sum += __shfl_xor(sum, 16);
        sum += __shfl_xor(sum, 32);
        // PV as two independent 4-deep chains (halves serial MFMA latency)
        f32x4 oA = zf, oB = zf;
        #pragma unroll
        for (int kt = 0; kt < 4; ++kt) {
            oA = __builtin_amdgcn_mfma_f32_16x16x16f16(pa[kt],     vb[kt],     oA, 0, 0, 0);
            oB = __builtin_amdgcn_mfma_f32_16x16x16f16(pa[kt + 4], vb[kt + 4], oB, 0, 0, 0);
        }
        f32x4 o = oA + oB;
        float rl = 1.f / sum;      // valid for q-column lr
        #pragma unroll
        for (int r = 0; r < 4; ++r) {
            float rs = __shfl(rl, lg * 4 + r);   // 1/sum for q-row lg*4+r
            aob[((size_t)qt * 16 + r) * 128] = (unsigned short)bf16_rne(o[r] * rs);
        }
    }
}

__global__ __launch_bounds__(512, 4) void axattn_attn(
    const float* __restrict__ x,
    const float* __restrict__ Wq,
    const float* __restrict__ Wk,
    const float* __restrict__ Wv,
    const float* __restrict__ Wo,
    unsigned short* __restrict__ Wob,
    unsigned short* __restrict__ AO)   // bf16 [(n0*128+w)][s][c]
{
    // bb = (((n0*4 + hp)*2 + wp)*8 + xcd ; w0 = xcd*16 + wp*8 ; h = hp*2, +1
    // wp-sibling blocks at delta-bb=8 -> same XCD -> share x cache lines.
    int bb  = blockIdx.x;
    int xcd = bb & 7;
    int k   = bb >> 3;
    int wp  = k & 1;
    int t2  = k >> 1;
    int hp  = t2 & 3;
    int n0  = t2 >> 2;
    int tid = threadIdx.x;
    int wvi = tid >> 6;        // wave 0..7 -> own problem (w)
    int l   = tid & 63;
    int lr  = l & 15;          // fragment row/col index
    int lg  = l >> 4;          // fragment k-group
    int w0  = xcd * 16 + wp * 8;
    int w   = w0 + wvi;
    int h0  = hp * 2;

    // folded prep: Wo fp32 -> bf16 (512 blocks x 32 = 16384 elements)
    if (tid < 32) {
        int i = bb * 32 + tid;
        Wob[i] = (unsigned short)bf16_rne(Wo[i]);
    }

    // two x-tile buffers: [w-local 0..7][row][c2], row stride 10 u32 (40B)
    __shared__ unsigned int xs[2][8 * 1280];   // 2 x 40 KB

    // Staging decomposition: q = w-quad (0/1 -> w0+q*4), row, c2b.
    int q   = tid & 1;
    int row = (tid >> 1) & 127;
    int c2b = tid >> 8;        // 0/1
    const float* gpb = x + ((size_t)(n0 * 128) * 128 + row) * 128 + w0 + q * 4;

    // ---- stage h0 into buf0 (batched loads, then pack+store) ----
    {
        const float* gp0 = gpb + (size_t)(h0 * 16) * 16384;
        float4 va[4], vb[4];
        #pragma unroll
        for (int it = 0; it < 4; ++it) {
            const float* gp = gp0 + (size_t)(2 * (it * 2 + c2b)) * 16384;
            va[it] = *(const float4*)gp;            // c-plane 2*c2
            vb[it] = *(const float4*)(gp + 16384);  // c-plane 2*c2+1
        }
        #pragma unroll
        for (int it = 0; it < 4; ++it) {
            int c2 = it * 2 + c2b;
            unsigned int* dp = xs[0] + (q * 4) * 1280 + row * 10 + c2;
            dp[0]    = pack_half2(va[it].x, vb[it].x);
            dp[1280] = pack_half2(va[it].y, vb[it].y);
            dp[2560] = pack_half2(va[it].z, vb[it].z);
            dp[3840] = pack_half2(va[it].w, vb[it].w);
        }
    }

    const float qsc = 0.088388347648318447f * 1.4426950408889634f; // 1/sqrt(128)*log2e

    // Weight fragments: lane reads W[lr][lg*4 .. +3] (overlaps staging).
    float4 wqf = *(const float4*)(Wq + lr * 16 + lg * 4);
    float4 wkf = *(const float4*)(Wk + lr * 16 + lg * 4);
    float4 wvf = *(const float4*)(Wv + lr * 16 + lg * 4);
    f16x4 fq = {(_Float16)wqf.x, (_Float16)wqf.y, (_Float16)wqf.z, (_Float16)wqf.w};
    f16x4 fk = {(_Float16)wkf.x, (_Float16)wkf.y, (_Float16)wkf.z, (_Float16)wkf.w};
    f16x4 fv = {(_Float16)wvf.x, (_Float16)wvf.y, (_Float16)wvf.z, (_Float16)wvf.w};

    __syncthreads();

    // ---- issue h1 loads NOW; consumed after compute(h0) (T14 overlap) ----
    float4 va1[4], vb1[4];
    {
        const float* gp1 = gpb + (size_t)((h0 + 1) * 16) * 16384;
        #pragma unroll
        for (int it = 0; it < 4; ++it) {
            const float* gp = gp1 + (size_t)(2 * (it * 2 + c2b)) * 16384;
            va1[it] = *(const float4*)gp;
            vb1[it] = *(const float4*)(gp + 16384);
        }
    }

    // ---- compute h0 (hides h1 HBM latency) ----
    unsigned short* aob0 = AO + ((size_t)(n0 * 128 + w) * 128 + lg * 4) * 128 + h0 * 16 + lr;
    attn_compute(xs[0], wvi, lr, lg, fq, fk, fv, qsc, aob0);

    // ---- pack+store h1 into buf1 ----
    #pragma unroll
    for (int it = 0; it < 4; ++it) {
        int c2 = it * 2 + c2b;
        unsigned int* dp = xs[1] + (q * 4) * 1280 + row * 10 + c2;
        dp[0]    = pack_half2(va1[it].x, vb1[it].x);
        dp[1280] = pack_half2(va1[it].y, vb1[it].y);
        dp[2560] = pack_half2(va1[it].z, vb1[it].z);
        dp[3840] = pack_half2(va1[it].w, vb1[it].w);
    }
    __syncthreads();

    // ---- compute h1 ----
    attn_compute(xs[1], wvi, lr, lg, fq, fk, fv, qsc, aob0 + 16);
}

// MFMA out-proj. Block = (n0, s, w-half); Wo A-frags preloaded to regs,
// AO half-tile staged to LDS (batched loads); 4 waves, wave wv:
// e-tile [wv*32,+32) x 64 w.
__global__ __launch_bounds__(256) void axattn_proj(
    const unsigned short* __restrict__ AOb,
    const unsigned short* __restrict__ Wob,
    const float* __restrict__ bo,
    float* __restrict__ out)
{
    int bb  = blockIdx.x;
    int wh  = bb & 1;
    int s   = (bb >> 1) & 127;
    int n0  = bb >> 8;
    int tid = threadIdx.x;
    int wv  = tid >> 6;
    int l   = tid & 63;
    int lr  = l & 15;
    int lg  = l >> 4;
    int lk  = lg * 8;
    int eb  = wv * 32;

    // AO half-tile [w-row 0..63][c 0..127] bf16, row stride 272B (256 + 16 pad)
    __shared__ char as_[64 * 272];

    // A-frags first: global loads overlap the LDS staging below.
    const unsigned short* wp_ = Wob + (size_t)(eb + lr) * 128 + lk;
    bf16x8 a0[4], a1[4];
    #pragma unroll
    for (int ct = 0; ct < 4; ++ct) {
        a0[ct] = *(const bf16x8*)(wp_ + ct * 32);
        a1[ct] = *(const bf16x8*)(wp_ + 16 * 128 + ct * 32);
    }

    // Batched staging: all 4 uint4 loads in flight before LDS stores.
    {
        uint4 t4[4];
        #pragma unroll
        for (int it = 0; it < 4; ++it) {
            int flat = it * 256 + tid;     // 0..1023
            int row  = flat >> 4;          // 0..63
            int seg  = flat & 15;
            t4[it] = *((const uint4*)(AOb
                + ((size_t)(n0 * 128 + wh * 64 + row) * 128 + s) * 128) + seg);
        }
        #pragma unroll
        for (int it = 0; it < 4; ++it) {
            int flat = it * 256 + tid;
            int row  = flat >> 4;
            int seg  = flat & 15;
            *(uint4*)(as_ + row * 272 + seg * 16) = t4[it];
        }
    }
    __syncthreads();

    f32x4 acc[2][4];
    #pragma unroll
    for (int mi = 0; mi < 2; ++mi)
        #pragma unroll
        for (int ni = 0; ni < 4; ++ni)
            acc[mi][ni] = (f32x4){0.f, 0.f, 0.f, 0.f};

    #pragma unroll
    for (int ct = 0; ct < 4; ++ct) {             // k = c tile of 32
        #pragma unroll
        for (int ni = 0; ni < 4; ++ni) {
            bf16x8 b = *(const bf16x8*)(as_ + (ni * 16 + lr) * 272 + (lk + ct * 32) * 2);
            acc[0][ni] = __builtin_amdgcn_mfma_f32_16x16x32_bf16(a0[ct], b, acc[0][ni], 0, 0, 0);
            acc[1][ni] = __builtin_amdgcn_mfma_f32_16x16x32_bf16(a1[ct], b, acc[1][ni], 0, 0, 0);
        }
    }

    int r4 = lg * 4;
    #pragma unroll
    for (int mi = 0; mi < 2; ++mi) {
        #pragma unroll
        for (int r = 0; r < 4; ++r) {
            int e = eb + mi * 16 + r4 + r;
            float bv = bo[e];
            float* orow = out + ((size_t)(n0 * 128 + e) * 128 + s) * 128 + wh * 64 + lr;
            #pragma unroll
            for (int ni = 0; ni < 4; ++ni)
                orow[ni * 16] = acc[mi][ni][r] + bv;
        }
    }
}

extern "C" void kernel_launch(void* const* d_in, const int* in_sizes, int n_in,
                              void* d_out, int out_size, void* d_ws, size_t ws_size,
                              hipStream_t stream) {
    const float* x  = (const float*)d_in[0];
    const float* Wq = (const float*)d_in[1];
    const float* Wk = (const float*)d_in[2];
    const float* Wv = (const float*)d_in[3];
    const float* Wo = (const float*)d_in[4];
    const float* bo = (const float*)d_in[5];
    float* out = (float*)d_out;

    unsigned short* AOb = (unsigned short*)d_ws;                        // 32 MiB bf16
    unsigned short* Wob = (unsigned short*)((char*)d_ws + (32u << 20)); // 32 KiB bf16

    axattn_attn<<<512, 512, 0, stream>>>(x, Wq, Wk, Wv, Wo, Wob, AOb);
    axattn_proj<<<2048, 256, 0, stream>>>(AOb, Wob, bo, out);
}

// Round 11
// 153.144 us; speedup vs baseline: 1.0968x; 1.0968x over previous
//
#include <hip/hip_runtime.h>
#include <hip/hip_fp16.h>

// AxialAttention on MI355X (gfx950).
// x: [8,128,128,128] fp32, attend along H. Problem = (n0,h,w): S=128, d=16.
// K1 (attn): fully-MFMA, round-5 geometry (measured best: 46us).
//   Block = 512 thr / 8 waves owns an 8-w stripe of one (n0,h); wp-sibling
//   blocks (delta-bb=8) land on the same XCD and consume the other half of
//   each 64B x line from L2. x staged to LDS as f16 (40KB -> 4 blocks/CU).
//   Fragment chain (D==A/B layout identity of 16x16x16 MFMA):
//     Q^T = mfma(Wq, y^T) (scaled by 1/sqrt(128)*log2e), K^T = mfma(Wk, y^T),
//     V = mfma(y, Wv^T), P^T = exp2(mfma(K, Q)) via cvt_pkrtz, O = mfma(P, V).
//   s_setprio(1) wraps the MFMA clusters (post-barrier waves are independent
//   -> T5 regime). AO epilogue packs via v_cvt_pk_bf16_f32 (RNE, 1 instr/2).
//   AO written bf16 [b=(n0,w)][s][c]. Wo->bf16 prep folded (16 elem/block).
//   __launch_bounds__(512,4): VGPR cap 128 (cap 64 = round-6 spill disaster;
//   round-10's h-pair pipelining = +16 VGPR, no overlap -> reverted).
// K2 (proj): block=(n0,s,w-half). Wo A-frags preloaded to regs, AO half-tile
//   staged to LDS (batched loads), 4 waves x (32e x 64w) 16x16x32 bf16 MFMA.

typedef __attribute__((ext_vector_type(4))) float f32x4;
typedef __attribute__((ext_vector_type(4))) _Float16 f16x4;
typedef __attribute__((ext_vector_type(2))) __fp16 fp16x2r;  // cvt_pkrtz native type
typedef __attribute__((ext_vector_type(8))) short bf16x8;

__device__ __forceinline__ unsigned int bf16_rne(float x) {
    unsigned int u = __float_as_uint(x);
    return (u + 0x7fffu + ((u >> 16) & 1u)) >> 16;
}
__device__ __forceinline__ unsigned int pack_half2(float a, float b) {
    __half2 h = __floats2half2_rn(a, b);
    return *reinterpret_cast<unsigned int*>(&h);
}

__global__ __launch_bounds__(512, 4) void axattn_attn(
    const float* __restrict__ x,
    const float* __restrict__ Wq,
    const float* __restrict__ Wk,
    const float* __restrict__ Wv,
    const float* __restrict__ Wo,
    unsigned short* __restrict__ Wob,
    unsigned short* __restrict__ AO)   // bf16 [(n0*128+w)][s][c]
{
    // bb = ((n0*8+h)*2 + wp)*8 + xcd ; w0 = xcd*16 + wp*8 ; wave wvi: w = w0+wvi
    // wp-sibling blocks (bb, bb+8) land on the same XCD -> share x cache lines.
    int bb  = blockIdx.x;
    int xcd = bb & 7;
    int k   = bb >> 3;         // (n0*8+h)*2 + wp
    int wp  = k & 1;
    int nh  = k >> 1;          // n0*8 + h
    int n0  = nh >> 3;
    int h   = nh & 7;
    int tid = threadIdx.x;
    int wvi = tid >> 6;        // wave 0..7 -> own problem (w)
    int l   = tid & 63;
    int lr  = l & 15;          // fragment row/col index
    int lg  = l >> 4;          // fragment k-group
    int w0  = xcd * 16 + wp * 8;
    int w   = w0 + wvi;

    // folded prep: Wo fp32 -> bf16 (1024 blocks x 16 = 16384 elements)
    if (tid < 16) {
        int i = bb * 16 + tid;
        Wob[i] = (unsigned short)bf16_rne(Wo[i]);
    }

    // x-tile as f16: [w-local 0..7][row][c2] ; row stride 10 u32 (40B)
    __shared__ unsigned int xs[8 * 1280];   // 40 KB

    // Staging: tid -> (q = w-quad 0/1, row, c2b); 4 c2 per thread.
    // Per wave-instr: lane pairs (q=0,1) cover 32B contiguous; 32 rows.
    {
        int q   = tid & 1;
        int row = (tid >> 1) & 127;
        int c2b = tid >> 8;    // 0/1
        const float* gp0 = x + ((size_t)(n0 * 128 + h * 16) * 128 + row) * 128 + w0 + q * 4;
        float4 va[4], vb[4];
        #pragma unroll
        for (int it = 0; it < 4; ++it) {
            const float* gp = gp0 + (size_t)(2 * (it * 2 + c2b)) * 16384;
            va[it] = *(const float4*)gp;            // c = 2*c2
            vb[it] = *(const float4*)(gp + 16384);  // c = 2*c2+1
        }
        #pragma unroll
        for (int it = 0; it < 4; ++it) {
            int c2 = it * 2 + c2b;
            unsigned int* dp = xs + (q * 4) * 1280 + row * 10 + c2;
            dp[0]    = pack_half2(va[it].x, vb[it].x);
            dp[1280] = pack_half2(va[it].y, vb[it].y);
            dp[2560] = pack_half2(va[it].z, vb[it].z);
            dp[3840] = pack_half2(va[it].w, vb[it].w);
        }
    }

    const float qsc = 0.088388347648318447f * 1.4426950408889634f; // 1/sqrt(128)*log2e
    const f32x4 zf = {0.f, 0.f, 0.f, 0.f};

    // Weight fragments: lane reads W[lr][lg*4 .. +3] (overlaps staging).
    float4 wqf = *(const float4*)(Wq + lr * 16 + lg * 4);
    float4 wkf = *(const float4*)(Wk + lr * 16 + lg * 4);
    float4 wvf = *(const float4*)(Wv + lr * 16 + lg * 4);
    f16x4 fq = {(_Float16)wqf.x, (_Float16)wqf.y, (_Float16)wqf.z, (_Float16)wqf.w};
    f16x4 fk = {(_Float16)wkf.x, (_Float16)wkf.y, (_Float16)wkf.z, (_Float16)wkf.w};
    f16x4 fv = {(_Float16)wvf.x, (_Float16)wvf.y, (_Float16)wvf.z, (_Float16)wvf.w};

    __syncthreads();

    // y fragments from LDS: yf[rt][j] = y[rt*16+lr][lg*4+j]
    const char* yb = (const char*)xs + wvi * 5120 + lr * 40 + lg * 8;
    f16x4 yf[8];
    #pragma unroll
    for (int rt = 0; rt < 8; ++rt)
        yf[rt] = *(const f16x4*)(yb + rt * 640);   // 16 rows * 40B

    // Projections: per 16-row tile t.
    f16x4 qb[8], ka[8], vb[8];
    #pragma unroll
    for (int t = 0; t < 8; ++t) {
        f32x4 qt = __builtin_amdgcn_mfma_f32_16x16x16f16(fq, yf[t], zf, 0, 0, 0);
        f32x4 kt = __builtin_amdgcn_mfma_f32_16x16x16f16(fk, yf[t], zf, 0, 0, 0);
        f32x4 vt = __builtin_amdgcn_mfma_f32_16x16x16f16(yf[t], fv, zf, 0, 0, 0);
        qb[t] = (f16x4){(_Float16)(qt[0] * qsc), (_Float16)(qt[1] * qsc),
                        (_Float16)(qt[2] * qsc), (_Float16)(qt[3] * qsc)};
        ka[t] = (f16x4){(_Float16)kt[0], (_Float16)kt[1], (_Float16)kt[2], (_Float16)kt[3]};
        vb[t] = (f16x4){(_Float16)vt[0], (_Float16)vt[1], (_Float16)vt[2], (_Float16)vt[3]};
    }

    // AO base for this lane: row q = qt*16 + lg*4 + r, col c = h*16 + lr.
    unsigned short* aob = AO + ((size_t)(n0 * 128 + w) * 128 + lg * 4) * 128 + h * 16 + lr;

    #pragma unroll
    for (int qt = 0; qt < 8; ++qt) {
        f32x4 s[8];
        __builtin_amdgcn_s_setprio(1);
        #pragma unroll
        for (int kt = 0; kt < 8; ++kt)
            s[kt] = __builtin_amdgcn_mfma_f32_16x16x16f16(ka[kt], qb[qt], zf, 0, 0, 0);
        __builtin_amdgcn_s_setprio(0);
        float sum = 0.f;
        f16x4 pa[8];
        #pragma unroll
        for (int kt = 0; kt < 8; ++kt) {
            float p0 = __builtin_amdgcn_exp2f(s[kt][0]);
            float p1 = __builtin_amdgcn_exp2f(s[kt][1]);
            float p2 = __builtin_amdgcn_exp2f(s[kt][2]);
            float p3 = __builtin_amdgcn_exp2f(s[kt][3]);
            sum += (p0 + p1) + (p2 + p3);
            union { fp16x2r h2[2]; f16x4 h4; } up;
            up.h2[0] = __builtin_amdgcn_cvt_pkrtz(p0, p1);
            up.h2[1] = __builtin_amdgcn_cvt_pkrtz(p2, p3);
            pa[kt] = up.h4;
        }
        sum += __shfl_xor(sum, 16);
        sum += __shfl_xor(sum, 32);
        // PV as two independent 4-deep chains (halves serial MFMA latency)
        f32x4 oA = zf, oB = zf;
        __builtin_amdgcn_s_setprio(1);
        #pragma unroll
        for (int kt = 0; kt < 4; ++kt) {
            oA = __builtin_amdgcn_mfma_f32_16x16x16f16(pa[kt],     vb[kt],     oA, 0, 0, 0);
            oB = __builtin_amdgcn_mfma_f32_16x16x16f16(pa[kt + 4], vb[kt + 4], oB, 0, 0, 0);
        }
        __builtin_amdgcn_s_setprio(0);
        f32x4 o = oA + oB;
        float rl = 1.f / sum;      // valid for q-column lr
        #pragma unroll
        for (int rp = 0; rp < 2; ++rp) {           // row pairs (RNE == bf16_rne)
            float rs0 = __shfl(rl, lg * 4 + 2 * rp);
            float rs1 = __shfl(rl, lg * 4 + 2 * rp + 1);
            float v0 = o[2 * rp] * rs0;
            float v1 = o[2 * rp + 1] * rs1;
            unsigned int u;
            asm("v_cvt_pk_bf16_f32 %0, %1, %2" : "=v"(u) : "v"(v0), "v"(v1));
            aob[((size_t)qt * 16 + 2 * rp) * 128]     = (unsigned short)u;
            aob[((size_t)qt * 16 + 2 * rp + 1) * 128] = (unsigned short)(u >> 16);
        }
    }
}

// MFMA out-proj. Block = (n0, s, w-half); Wo A-frags preloaded to regs,
// AO half-tile staged to LDS (batched loads); 4 waves, wave wv:
// e-tile [wv*32,+32) x 64 w.
__global__ __launch_bounds__(256) void axattn_proj(
    const unsigned short* __restrict__ AOb,
    const unsigned short* __restrict__ Wob,
    const float* __restrict__ bo,
    float* __restrict__ out)
{
    int bb  = blockIdx.x;
    int wh  = bb & 1;
    int s   = (bb >> 1) & 127;
    int n0  = bb >> 8;
    int tid = threadIdx.x;
    int wv  = tid >> 6;
    int l   = tid & 63;
    int lr  = l & 15;
    int lg  = l >> 4;
    int lk  = lg * 8;
    int eb  = wv * 32;

    // AO half-tile [w-row 0..63][c 0..127] bf16, row stride 272B (256 + 16 pad)
    __shared__ char as_[64 * 272];

    // A-frags first: global loads overlap the LDS staging below.
    const unsigned short* wp_ = Wob + (size_t)(eb + lr) * 128 + lk;
    bf16x8 a0[4], a1[4];
    #pragma unroll
    for (int ct = 0; ct < 4; ++ct) {
        a0[ct] = *(const bf16x8*)(wp_ + ct * 32);
        a1[ct] = *(const bf16x8*)(wp_ + 16 * 128 + ct * 32);
    }

    // Batched staging: all 4 uint4 loads in flight before LDS stores.
    {
        uint4 t4[4];
        #pragma unroll
        for (int it = 0; it < 4; ++it) {
            int flat = it * 256 + tid;     // 0..1023
            int row  = flat >> 4;          // 0..63
            int seg  = flat & 15;
            t4[it] = *((const uint4*)(AOb
                + ((size_t)(n0 * 128 + wh * 64 + row) * 128 + s) * 128) + seg);
        }
        #pragma unroll
        for (int it = 0; it < 4; ++it) {
            int flat = it * 256 + tid;
            int row  = flat >> 4;
            int seg  = flat & 15;
            *(uint4*)(as_ + row * 272 + seg * 16) = t4[it];
        }
    }
    __syncthreads();

    f32x4 acc[2][4];
    #pragma unroll
    for (int mi = 0; mi < 2; ++mi)
        #pragma unroll
        for (int ni = 0; ni < 4; ++ni)
            acc[mi][ni] = (f32x4){0.f, 0.f, 0.f, 0.f};

    #pragma unroll
    for (int ct = 0; ct < 4; ++ct) {             // k = c tile of 32
        #pragma unroll
        for (int ni = 0; ni < 4; ++ni) {
            bf16x8 b = *(const bf16x8*)(as_ + (ni * 16 + lr) * 272 + (lk + ct * 32) * 2);
            acc[0][ni] = __builtin_amdgcn_mfma_f32_16x16x32_bf16(a0[ct], b, acc[0][ni], 0, 0, 0);
            acc[1][ni] = __builtin_amdgcn_mfma_f32_16x16x32_bf16(a1[ct], b, acc[1][ni], 0, 0, 0);
        }
    }

    int r4 = lg * 4;
    #pragma unroll
    for (int mi = 0; mi < 2; ++mi) {
        #pragma unroll
        for (int r = 0; r < 4; ++r) {
            int e = eb + mi * 16 + r4 + r;
            float bv = bo[e];
            float* orow = out + ((size_t)(n0 * 128 + e) * 128 + s) * 128 + wh * 64 + lr;
            #pragma unroll
            for (int ni = 0; ni < 4; ++ni)
                orow[ni * 16] = acc[mi][ni][r] + bv;
        }
    }
}

extern "C" void kernel_launch(void* const* d_in, const int* in_sizes, int n_in,
                              void* d_out, int out_size, void* d_ws, size_t ws_size,
                              hipStream_t stream) {
    const float* x  = (const float*)d_in[0];
    const float* Wq = (const float*)d_in[1];
    const float* Wk = (const float*)d_in[2];
    const float* Wv = (const float*)d_in[3];
    const float* Wo = (const float*)d_in[4];
    const float* bo = (const float*)d_in[5];
    float* out = (float*)d_out;

    unsigned short* AOb = (unsigned short*)d_ws;                        // 32 MiB bf16
    unsigned short* Wob = (unsigned short*)((char*)d_ws + (32u << 20)); // 32 KiB bf16

    axattn_attn<<<1024, 512, 0, stream>>>(x, Wq, Wk, Wv, Wo, Wob, AOb);
    axattn_proj<<<2048, 256, 0, stream>>>(AOb, Wob, bo, out);
}